// Round 1
// baseline (301.003 us; speedup 1.0000x reference)
//
#include <hip/hip_runtime.h>

#define LN_EPS 1e-5f

// One edge per 16-lane group (4 edges/wave). Lane l of a group loads 64 B
// (4x float4) of the 1024 B concat(h[src],h[dst]) row pair, accumulates
// s=SUM(e), q=SUM(e^2), a=SUM(e*gamma*W) in-registers, then a 4-step
// shfl_xor butterfly (masks 1/2/4/8, within a 16-lane DPP row) reduces per
// group. score = rs*(a - mu*sum_gw) + (SUM(beta*W) + b).
__global__ __launch_bounds__(256)
void edge_ln_score_kernel(const float* __restrict__ h,
                          const int* __restrict__ src,
                          const int* __restrict__ dst,
                          const float* __restrict__ gamma,
                          const float* __restrict__ beta,
                          const float* __restrict__ W,
                          const float* __restrict__ bias,
                          float* __restrict__ out,
                          int E)
{
    const int tid  = threadIdx.x;
    const int lane = tid & 63;
    const int l    = lane & 15;   // lane within edge-group
    const int grp  = lane >> 4;   // edge-group 0..3 within wave

    const int waveInBlock   = tid >> 6;
    const int wavesPerBlock = blockDim.x >> 6;
    const int gwave      = blockIdx.x * wavesPerBlock + waveInBlock;
    const int waveStride = gridDim.x * wavesPerBlock;

    // Per-lane gamma*W fragment: features l*4 + 64*k, k=0..3 (matches v0..v3)
    const float4* g4 = (const float4*)gamma;
    const float4* b4 = (const float4*)beta;
    const float4* w4 = (const float4*)W;

    float4 gw[4];
    float gwsum = 0.0f, bwsum = 0.0f;
#pragma unroll
    for (int k = 0; k < 4; ++k) {
        float4 gg = g4[l + 16 * k];
        float4 ww = w4[l + 16 * k];
        float4 bb = b4[l + 16 * k];
        float4 r;
        r.x = gg.x * ww.x; r.y = gg.y * ww.y;
        r.z = gg.z * ww.z; r.w = gg.w * ww.w;
        gw[k] = r;
        gwsum += (r.x + r.y) + (r.z + r.w);
        bwsum += (bb.x * ww.x + bb.y * ww.y) + (bb.z * ww.z + bb.w * ww.w);
    }
    // One-time full-wave reduction; each feature appears once per group (4x).
#pragma unroll
    for (int m = 1; m < 64; m <<= 1) {
        gwsum += __shfl_xor(gwsum, m, 64);
        bwsum += __shfl_xor(bwsum, m, 64);
    }
    const float sum_gw = 0.25f * gwsum;
    const float cbeta  = fmaf(0.25f, bwsum, bias[0]);
    const float inv_d  = 1.0f / 256.0f;

    for (int base = gwave * 4; base < E; base += waveStride * 4) {
        int e  = base + grp;
        int ec = (e < E) ? e : (E - 1);   // clamp (E%4==0 so normally all valid)
        int si = src[ec];
        int di = dst[ec];
        const float4* hs = (const float4*)h + si * 32;
        const float4* hd = (const float4*)h + di * 32;
        float4 v0 = hs[l];        // e[l*4 .. l*4+3]
        float4 v1 = hs[l + 16];   // e[64 + l*4 ..]
        float4 v2 = hd[l];        // e[128 + l*4 ..]
        float4 v3 = hd[l + 16];   // e[192 + l*4 ..]

        float s = ((v0.x + v0.y) + (v0.z + v0.w))
                + ((v1.x + v1.y) + (v1.z + v1.w))
                + ((v2.x + v2.y) + (v2.z + v2.w))
                + ((v3.x + v3.y) + (v3.z + v3.w));

        float q = 0.0f;
        q = fmaf(v0.x, v0.x, q); q = fmaf(v0.y, v0.y, q);
        q = fmaf(v0.z, v0.z, q); q = fmaf(v0.w, v0.w, q);
        q = fmaf(v1.x, v1.x, q); q = fmaf(v1.y, v1.y, q);
        q = fmaf(v1.z, v1.z, q); q = fmaf(v1.w, v1.w, q);
        q = fmaf(v2.x, v2.x, q); q = fmaf(v2.y, v2.y, q);
        q = fmaf(v2.z, v2.z, q); q = fmaf(v2.w, v2.w, q);
        q = fmaf(v3.x, v3.x, q); q = fmaf(v3.y, v3.y, q);
        q = fmaf(v3.z, v3.z, q); q = fmaf(v3.w, v3.w, q);

        float a = 0.0f;
        a = fmaf(v0.x, gw[0].x, a); a = fmaf(v0.y, gw[0].y, a);
        a = fmaf(v0.z, gw[0].z, a); a = fmaf(v0.w, gw[0].w, a);
        a = fmaf(v1.x, gw[1].x, a); a = fmaf(v1.y, gw[1].y, a);
        a = fmaf(v1.z, gw[1].z, a); a = fmaf(v1.w, gw[1].w, a);
        a = fmaf(v2.x, gw[2].x, a); a = fmaf(v2.y, gw[2].y, a);
        a = fmaf(v2.z, gw[2].z, a); a = fmaf(v2.w, gw[2].w, a);
        a = fmaf(v3.x, gw[3].x, a); a = fmaf(v3.y, gw[3].y, a);
        a = fmaf(v3.z, gw[3].z, a); a = fmaf(v3.w, gw[3].w, a);

        // 16-lane butterfly: masks 1,2,4,8 stay within the group.
#pragma unroll
        for (int m = 1; m < 16; m <<= 1) {
            s += __shfl_xor(s, m, 64);
            q += __shfl_xor(q, m, 64);
            a += __shfl_xor(a, m, 64);
        }

        float mu    = s * inv_d;
        float var   = fmaf(-mu, mu, q * inv_d);
        float rs    = rsqrtf(var + LN_EPS);
        float score = fmaf(rs, fmaf(-mu, sum_gw, a), cbeta);

        if (l == 0 && e < E) out[e] = score;
    }
}

extern "C" void kernel_launch(void* const* d_in, const int* in_sizes, int n_in,
                              void* d_out, int out_size, void* d_ws, size_t ws_size,
                              hipStream_t stream) {
    const float* h     = (const float*)d_in[0];
    const int*   src   = (const int*)d_in[1];
    const int*   dst   = (const int*)d_in[2];
    const float* gamma = (const float*)d_in[3];
    const float* beta  = (const float*)d_in[4];
    const float* W     = (const float*)d_in[5];
    const float* b     = (const float*)d_in[6];
    float* out = (float*)d_out;
    const int E = in_sizes[1];

    dim3 grid(2048), block(256);
    hipLaunchKernelGGL(edge_ln_score_kernel, grid, block, 0, stream,
                       h, src, dst, gamma, beta, W, b, out, E);
}

// Round 2
// 119.695 us; speedup vs baseline: 2.5148x; 2.5148x over previous
//
#include <hip/hip_runtime.h>

#define LN_EPS 1e-5f

// ---------------- Pass 1: per-node precompute ----------------
// table[n] = {S, Q, A_lo, A_hi} where
//   S    = sum_j h[n][j]
//   Q    = sum_j h[n][j]^2
//   A_lo = sum_j h[n][j] * gamma[j]     * W[j]        (node used as src)
//   A_hi = sum_j h[n][j] * gamma[j+128] * W[j+128]    (node used as dst)
// 32 lanes per node (2 nodes / wave), each lane one float4 of the 512 B row.
// Block 0 / wave 0 additionally computes consts = {sum(gamma*W), sum(beta*W)+b}.
__global__ __launch_bounds__(256)
void node_precompute_kernel(const float* __restrict__ h,
                            const float* __restrict__ gamma,
                            const float* __restrict__ beta,
                            const float* __restrict__ W,
                            const float* __restrict__ bias,
                            float4* __restrict__ table,
                            float* __restrict__ consts,
                            int N)
{
    const int tid  = threadIdx.x;
    const int lane = tid & 63;
    const int l    = lane & 31;   // lane within node
    const int half = lane >> 5;   // which node of the wave's pair

    const float4* g4 = (const float4*)gamma;
    const float4* b4 = (const float4*)beta;
    const float4* w4 = (const float4*)W;

    if (blockIdx.x == 0 && tid < 64) {
        float4 gg = g4[tid], ww = w4[tid], bb = b4[tid];
        float gwsum = (gg.x * ww.x + gg.y * ww.y) + (gg.z * ww.z + gg.w * ww.w);
        float bwsum = (bb.x * ww.x + bb.y * ww.y) + (bb.z * ww.z + bb.w * ww.w);
#pragma unroll
        for (int m = 1; m < 64; m <<= 1) {
            gwsum += __shfl_xor(gwsum, m, 64);
            bwsum += __shfl_xor(bwsum, m, 64);
        }
        if (tid == 0) { consts[0] = gwsum; consts[1] = bwsum + bias[0]; }
    }

    // gamma*W fragments for this lane's 4-feature slice (lo half / hi half)
    float4 glo = g4[l],      wlo = w4[l];
    float4 ghi = g4[l + 32], whi = w4[l + 32];
    float4 gwlo = {glo.x * wlo.x, glo.y * wlo.y, glo.z * wlo.z, glo.w * wlo.w};
    float4 gwhi = {ghi.x * whi.x, ghi.y * whi.y, ghi.z * whi.z, ghi.w * whi.w};

    const int waveInBlock = tid >> 6;
    const int node = (blockIdx.x * 4 + waveInBlock) * 2 + half;
    if (node >= N) return;

    const float4* row = (const float4*)h + (size_t)node * 32;
    float4 v = row[l];

    float s = (v.x + v.y) + (v.z + v.w);
    float q = fmaf(v.x, v.x, fmaf(v.y, v.y, fmaf(v.z, v.z, v.w * v.w)));
    float alo = fmaf(v.x, gwlo.x, fmaf(v.y, gwlo.y, fmaf(v.z, gwlo.z, v.w * gwlo.w)));
    float ahi = fmaf(v.x, gwhi.x, fmaf(v.y, gwhi.y, fmaf(v.z, gwhi.z, v.w * gwhi.w)));

    // Butterfly over the 32 lanes of this node (masks stay within the half).
#pragma unroll
    for (int m = 1; m < 32; m <<= 1) {
        s   += __shfl_xor(s,   m, 64);
        q   += __shfl_xor(q,   m, 64);
        alo += __shfl_xor(alo, m, 64);
        ahi += __shfl_xor(ahi, m, 64);
    }
    if (l == 0) table[node] = make_float4(s, q, alo, ahi);
}

// ---------------- Pass 2: per-edge scoring ----------------
// One thread per edge: two 16 B gathers from the L2-resident node table.
__global__ __launch_bounds__(256)
void edge_score_kernel(const int* __restrict__ src,
                       const int* __restrict__ dst,
                       const float4* __restrict__ table,
                       const float* __restrict__ consts,
                       float* __restrict__ out,
                       int E)
{
    const int e = blockIdx.x * blockDim.x + threadIdx.x;
    if (e >= E) return;

    const float sum_gw = consts[0];
    const float cbeta  = consts[1];

    const int si = src[e];
    const int di = dst[e];
    float4 ts = table[si];
    float4 td = table[di];

    const float inv_d = 1.0f / 256.0f;
    float s = ts.x + td.x;
    float q = ts.y + td.y;
    float a = ts.z + td.w;   // A_lo[src] + A_hi[dst]

    float mu  = s * inv_d;
    float var = fmaf(-mu, mu, q * inv_d);
    float rs  = rsqrtf(var + LN_EPS);
    out[e] = fmaf(rs, fmaf(-mu, sum_gw, a), cbeta);
}

// ---------------- Fallback (R1 kernel) if ws too small ----------------
__global__ __launch_bounds__(256)
void edge_ln_score_fallback(const float* __restrict__ h,
                            const int* __restrict__ src,
                            const int* __restrict__ dst,
                            const float* __restrict__ gamma,
                            const float* __restrict__ beta,
                            const float* __restrict__ W,
                            const float* __restrict__ bias,
                            float* __restrict__ out,
                            int E)
{
    const int tid  = threadIdx.x;
    const int lane = tid & 63;
    const int l    = lane & 15;
    const int grp  = lane >> 4;

    const int waveInBlock   = tid >> 6;
    const int wavesPerBlock = blockDim.x >> 6;
    const int gwave      = blockIdx.x * wavesPerBlock + waveInBlock;
    const int waveStride = gridDim.x * wavesPerBlock;

    const float4* g4 = (const float4*)gamma;
    const float4* b4 = (const float4*)beta;
    const float4* w4 = (const float4*)W;

    float4 gw[4];
    float gwsum = 0.0f, bwsum = 0.0f;
#pragma unroll
    for (int k = 0; k < 4; ++k) {
        float4 gg = g4[l + 16 * k];
        float4 ww = w4[l + 16 * k];
        float4 bb = b4[l + 16 * k];
        float4 r;
        r.x = gg.x * ww.x; r.y = gg.y * ww.y;
        r.z = gg.z * ww.z; r.w = gg.w * ww.w;
        gw[k] = r;
        gwsum += (r.x + r.y) + (r.z + r.w);
        bwsum += (bb.x * ww.x + bb.y * ww.y) + (bb.z * ww.z + bb.w * ww.w);
    }
#pragma unroll
    for (int m = 1; m < 64; m <<= 1) {
        gwsum += __shfl_xor(gwsum, m, 64);
        bwsum += __shfl_xor(bwsum, m, 64);
    }
    const float sum_gw = 0.25f * gwsum;
    const float cbeta  = fmaf(0.25f, bwsum, bias[0]);
    const float inv_d  = 1.0f / 256.0f;

    for (int base = gwave * 4; base < E; base += waveStride * 4) {
        int e  = base + grp;
        int ec = (e < E) ? e : (E - 1);
        int si = src[ec];
        int di = dst[ec];
        const float4* hs = (const float4*)h + si * 32;
        const float4* hd = (const float4*)h + di * 32;
        float4 v0 = hs[l];
        float4 v1 = hs[l + 16];
        float4 v2 = hd[l];
        float4 v3 = hd[l + 16];

        float s = ((v0.x + v0.y) + (v0.z + v0.w))
                + ((v1.x + v1.y) + (v1.z + v1.w))
                + ((v2.x + v2.y) + (v2.z + v2.w))
                + ((v3.x + v3.y) + (v3.z + v3.w));
        float q = 0.0f;
        q = fmaf(v0.x, v0.x, q); q = fmaf(v0.y, v0.y, q);
        q = fmaf(v0.z, v0.z, q); q = fmaf(v0.w, v0.w, q);
        q = fmaf(v1.x, v1.x, q); q = fmaf(v1.y, v1.y, q);
        q = fmaf(v1.z, v1.z, q); q = fmaf(v1.w, v1.w, q);
        q = fmaf(v2.x, v2.x, q); q = fmaf(v2.y, v2.y, q);
        q = fmaf(v2.z, v2.z, q); q = fmaf(v2.w, v2.w, q);
        q = fmaf(v3.x, v3.x, q); q = fmaf(v3.y, v3.y, q);
        q = fmaf(v3.z, v3.z, q); q = fmaf(v3.w, v3.w, q);
        float a = 0.0f;
        a = fmaf(v0.x, gw[0].x, a); a = fmaf(v0.y, gw[0].y, a);
        a = fmaf(v0.z, gw[0].z, a); a = fmaf(v0.w, gw[0].w, a);
        a = fmaf(v1.x, gw[1].x, a); a = fmaf(v1.y, gw[1].y, a);
        a = fmaf(v1.z, gw[1].z, a); a = fmaf(v1.w, gw[1].w, a);
        a = fmaf(v2.x, gw[2].x, a); a = fmaf(v2.y, gw[2].y, a);
        a = fmaf(v2.z, gw[2].z, a); a = fmaf(v2.w, gw[2].w, a);
        a = fmaf(v3.x, gw[3].x, a); a = fmaf(v3.y, gw[3].y, a);
        a = fmaf(v3.z, gw[3].z, a); a = fmaf(v3.w, gw[3].w, a);
#pragma unroll
        for (int m = 1; m < 16; m <<= 1) {
            s += __shfl_xor(s, m, 64);
            q += __shfl_xor(q, m, 64);
            a += __shfl_xor(a, m, 64);
        }
        float mu    = s * inv_d;
        float var   = fmaf(-mu, mu, q * inv_d);
        float rs    = rsqrtf(var + LN_EPS);
        float score = fmaf(rs, fmaf(-mu, sum_gw, a), cbeta);
        if (l == 0 && e < E) out[e] = score;
    }
}

extern "C" void kernel_launch(void* const* d_in, const int* in_sizes, int n_in,
                              void* d_out, int out_size, void* d_ws, size_t ws_size,
                              hipStream_t stream) {
    const float* h     = (const float*)d_in[0];
    const int*   src   = (const int*)d_in[1];
    const int*   dst   = (const int*)d_in[2];
    const float* gamma = (const float*)d_in[3];
    const float* beta  = (const float*)d_in[4];
    const float* W     = (const float*)d_in[5];
    const float* b     = (const float*)d_in[6];
    float* out = (float*)d_out;
    const int E = in_sizes[1];
    const int N = in_sizes[0] / 128;

    const size_t ws_needed = (size_t)N * 16 + 16;
    if (ws_size < ws_needed) {
        // Safety net: single-pass gather kernel (R1).
        hipLaunchKernelGGL(edge_ln_score_fallback, dim3(2048), dim3(256), 0, stream,
                           h, src, dst, gamma, beta, W, b, out, E);
        return;
    }

    float4* table = (float4*)d_ws;
    float*  consts = (float*)((char*)d_ws + (size_t)N * 16);

    // Pass 1: 8 nodes / block (4 waves x 2 nodes)
    int blocks1 = (N + 7) / 8;
    hipLaunchKernelGGL(node_precompute_kernel, dim3(blocks1), dim3(256), 0, stream,
                       h, gamma, beta, W, b, table, consts, N);

    // Pass 2: 1 thread / edge
    int blocks2 = (E + 255) / 256;
    hipLaunchKernelGGL(edge_score_kernel, dim3(blocks2), dim3(256), 0, stream,
                       src, dst, table, consts, out, E);
}